// Round 12
// baseline (865.083 us; speedup 1.0000x reference)
//
#include <hip/hip_runtime.h>

#define NB 2048
#define NT 128

typedef float v2f __attribute__((ext_vector_type(2)));

static __device__ __forceinline__ v2f pkfma(v2f a, v2f b, v2f c) {
#if __has_builtin(__builtin_elementwise_fma)
    return __builtin_elementwise_fma(a, b, c);
#else
    v2f r; r.x = fmaf(a.x, b.x, c.x); r.y = fmaf(a.y, b.y, c.y); return r;
#endif
}
static __device__ __forceinline__ v2f mkv2(float x, float y) { v2f r; r.x = x; r.y = y; return r; }

// ---------------------------------------------------------------------------
// Kernel 1: action-latent MLP  (B*T, 8) -> relu(64) -> (B*T, 16), into d_ws
// ---------------------------------------------------------------------------
__global__ __launch_bounds__(256, 4) void acl_kernel(
    const float* __restrict__ acs, const float* __restrict__ acW0,
    const float* __restrict__ acb0, const float* __restrict__ acW1,
    const float* __restrict__ acb1, float* __restrict__ aclout)
{
    __shared__ float sW0[64 * 8];
    __shared__ float sW1[16 * 64];
    __shared__ float sB0[64];
    __shared__ float sB1[16];
    const int tid = threadIdx.x;
    for (int i = tid; i < 64 * 8; i += 256) sW0[i] = acW0[i];
    for (int i = tid; i < 16 * 64; i += 256) sW1[i] = acW1[i];
    if (tid < 64) sB0[tid] = acb0[tid];
    if (tid < 16) sB1[tid] = acb1[tid];
    __syncthreads();

    const int row = blockIdx.x * 256 + tid;
    const float4 x0 = *(const float4*)&acs[row * 8];
    const float4 x1 = *(const float4*)&acs[row * 8 + 4];

    float o[16];
    #pragma unroll
    for (int m = 0; m < 16; ++m) o[m] = sB1[m];

    #pragma unroll
    for (int jc = 0; jc < 16; ++jc) {
        float hq[4];
        #pragma unroll
        for (int u = 0; u < 4; ++u) {
            const int j = jc * 4 + u;
            const float4 wa = *(const float4*)&sW0[j * 8];
            const float4 wb = *(const float4*)&sW0[j * 8 + 4];
            float hv = sB0[j];
            hv = fmaf(x0.x, wa.x, hv); hv = fmaf(x0.y, wa.y, hv);
            hv = fmaf(x0.z, wa.z, hv); hv = fmaf(x0.w, wa.w, hv);
            hv = fmaf(x1.x, wb.x, hv); hv = fmaf(x1.y, wb.y, hv);
            hv = fmaf(x1.z, wb.z, hv); hv = fmaf(x1.w, wb.w, hv);
            hq[u] = fmaxf(hv, 0.f);
        }
        #pragma unroll
        for (int m = 0; m < 16; ++m) {
            const float4 wv = *(const float4*)&sW1[m * 64 + jc * 4];
            o[m] = fmaf(hq[0], wv.x, o[m]);
            o[m] = fmaf(hq[1], wv.y, o[m]);
            o[m] = fmaf(hq[2], wv.z, o[m]);
            o[m] = fmaf(hq[3], wv.w, o[m]);
        }
    }
    float4* op = (float4*)&aclout[row * 16];
    op[0] = make_float4(o[0],  o[1],  o[2],  o[3]);
    op[1] = make_float4(o[4],  o[5],  o[6],  o[7]);
    op[2] = make_float4(o[8],  o[9],  o[10], o[11]);
    op[3] = make_float4(o[12], o[13], o[14], o[15]);
}

// ---------------------------------------------------------------------------
// Kernel 2 v13: DUAL-ELEMENT waves. Each wave integrates 2 batch elements
// (independent software streams sharing M/W1/wa/vj registers); every LDS
// round trip is fused across the pair so stream B's issue fills stream A's
// latency. Grid 256 blocks (1/CU, single round; v11's measured-good 4
// waves/CU regime). Structure: v12's ystar recurrence + full-row gproj.
// ---------------------------------------------------------------------------
__global__ __launch_bounds__(256, 1) void ode_kernel(
    const float* __restrict__ encW0, const float* __restrict__ encb0,
    const float* __restrict__ encW1, const float* __restrict__ encb1,
    const float* __restrict__ dynW0, const float* __restrict__ dynb0,
    const float* __restrict__ dynW1, const float* __restrict__ dynb1,
    const float* __restrict__ ob,    const float* __restrict__ times,
    const float* __restrict__ aclws, float* __restrict__ yio)
{
    __shared__ float sEncW0T[64 * 64];   // [k][j]
    __shared__ float sEncW1T[64 * 32];   // [j][m]
    __shared__ float sW0s[64 * 32];      // W0y rows: [j][m]
    __shared__ float sW1T[64 * 32];      // W1 cols:  [j'][m]
    __shared__ float sM[64 * 64];        // M[j][j'] = sum_m W0y[j][m] W1[m][j']
    __shared__ float sEncB0[64], sEncB1[32], sB1d[32];
    __shared__ float xbuf[8][64];
    __shared__ float hbuf[8][64];
    __shared__ float tbuf[8 * NT];

    const int tid = threadIdx.x;
    for (int i = tid; i < 64 * 64; i += 256) { int r = i >> 6, c = i & 63; sEncW0T[c * 64 + r] = encW0[i]; }
    for (int i = tid; i < 32 * 64; i += 256) { int r = i >> 6, c = i & 63; sEncW1T[c * 32 + r] = encW1[i]; }
    for (int i = tid; i < 64 * 32; i += 256) { int j = i >> 5, mm = i & 31; sW0s[i] = dynW0[j * 48 + mm]; }
    for (int i = tid; i < 64 * 32; i += 256) { int c = i >> 5, mm = i & 31; sW1T[i] = dynW1[mm * 64 + c]; }
    for (int i = tid; i < 8 * NT; i += 256) tbuf[i] = times[(size_t)blockIdx.x * 8 * NT + i];
    if (tid < 64) { sEncB0[tid] = encb0[tid]; }
    if (tid < 32) { sEncB1[tid] = encb1[tid]; sB1d[tid] = dynb1[tid]; }
    __syncthreads();

    // ---- compute sM cooperatively: thread t -> row j = t>>2, 16 cols
    {
        const int j  = tid >> 2;
        const int cg = (tid & 3) * 16;
        float4 wr[8];
        #pragma unroll
        for (int q = 0; q < 8; ++q) wr[q] = *(const float4*)&sW0s[j * 32 + q * 4];
        #pragma unroll 2
        for (int k = 0; k < 16; ++k) {
            const int c = cg + k;
            v2f s0 = mkv2(0.f, 0.f), s1 = mkv2(0.f, 0.f);
            #pragma unroll
            for (int q = 0; q < 8; ++q) {
                const float4 t4 = *(const float4*)&sW1T[c * 32 + q * 4];
                s0 = pkfma(mkv2(t4.x, t4.y), mkv2(wr[q].x, wr[q].y), s0);
                s1 = pkfma(mkv2(t4.z, t4.w), mkv2(wr[q].z, wr[q].w), s1);
            }
            sM[j * 64 + c] = (s0.x + s1.x) + (s0.y + s1.y);
        }
    }
    __syncthreads();

    const int w    = tid >> 6;
    const int lane = tid & 63;
    const int e0   = w * 2;
    const int bu0  = __builtin_amdgcn_readfirstlane(blockIdx.x * 8 + e0);
    const int bu1  = bu0 + 1;
    const int m    = lane & 31;
    const int H    = lane & 32;

    float* __restrict__ xbA = xbuf[e0];
    float* __restrict__ xbB = xbuf[e0 + 1];
    float* __restrict__ hbA = hbuf[e0];
    float* __restrict__ hbB = hbuf[e0 + 1];

    // M FULL row for this lane (shared by both streams)
    float Mf[64];
    #pragma unroll
    for (int q = 0; q < 16; ++q) *(float4*)&Mf[q * 4] = *(const float4*)&sM[lane * 64 + q * 4];
    const v2f* Mp = (const v2f*)Mf;

    // W1 half-row for y-update (shared)
    float w1rf[32];
    #pragma unroll
    for (int q = 0; q < 8; ++q)  *(float4*)&w1rf[q * 4] = *(const float4*)&dynW1[m * 64 + H + q * 4];
    const v2f* w1r = (const v2f*)w1rf;

    // acl columns of W0 row lane (shared)
    float wa[16];
    #pragma unroll
    for (int q = 0; q < 4; ++q) *(float4*)&wa[q * 4] = *(const float4*)&dynW0[lane * 48 + 32 + q * 4];
    const float b0r = dynb0[lane];
    const float b1r = dynb1[m];

    // vj = W0y[lane,:] . b1  (shared; transient global reads)
    float vj = 0.f;
    #pragma unroll
    for (int q = 0; q < 8; ++q) {
        const float4 wv = *(const float4*)&dynW0[lane * 48 + q * 4];
        vj = fmaf(wv.x, sB1d[q * 4 + 0], vj); vj = fmaf(wv.y, sB1d[q * 4 + 1], vj);
        vj = fmaf(wv.z, sB1d[q * 4 + 2], vj); vj = fmaf(wv.w, sB1d[q * 4 + 3], vj);
    }

    // dual g-projection: gX = M[lane,:].hX + vj (raw, caller scales by hh)
    auto gproj2 = [&](float hA, float hB, float& gA, float& gB) {
        __builtin_amdgcn_wave_barrier();
        hbA[lane] = hA;
        hbB[lane] = hB;
        __builtin_amdgcn_wave_barrier();
        v2f A0 = mkv2(0.f, 0.f), A1 = mkv2(0.f, 0.f);
        v2f B0 = mkv2(0.f, 0.f), B1 = mkv2(0.f, 0.f);
        #pragma unroll
        for (int c = 0; c < 4; ++c) {
            float hrA[16], hrB[16];
            #pragma unroll
            for (int q = 0; q < 4; ++q) *(float4*)&hrA[q * 4] = *(const float4*)&hbA[c * 16 + q * 4];
            #pragma unroll
            for (int q = 0; q < 4; ++q) *(float4*)&hrB[q * 4] = *(const float4*)&hbB[c * 16 + q * 4];
            const v2f* hpA = (const v2f*)hrA;
            const v2f* hpB = (const v2f*)hrB;
            const v2f* mp  = Mp + c * 8;
            #pragma unroll
            for (int q = 0; q < 8; q += 2) {
                A0 = pkfma(hpA[q],     mp[q],     A0);
                A1 = pkfma(hpA[q + 1], mp[q + 1], A1);
                B0 = pkfma(hpB[q],     mp[q],     B0);
                B1 = pkfma(hpB[q + 1], mp[q + 1], B1);
            }
        }
        const v2f SA = A0 + A1;
        const v2f SB = B0 + B1;
        gA = SA.x + SA.y + vj;
        gB = SB.x + SB.y + vj;
    };

    // ---- encoder (one-time, per element): ob(64) -> relu(64) -> y(32)
    auto encode = [&](int bu, float* xb, float* hb) -> float {
        __builtin_amdgcn_wave_barrier();
        xb[lane] = ob[bu * 64 + lane];
        __builtin_amdgcn_wave_barrier();
        float4 xv[16];
        #pragma unroll
        for (int q = 0; q < 16; ++q) xv[q] = *(const float4*)&xb[q * 4];
        float a0 = sEncB0[lane], a1 = 0.f, a2 = 0.f, a3 = 0.f;
        #pragma unroll
        for (int q = 0; q < 16; ++q) {
            a0 = fmaf(xv[q].x, sEncW0T[(q * 4 + 0) * 64 + lane], a0);
            a1 = fmaf(xv[q].y, sEncW0T[(q * 4 + 1) * 64 + lane], a1);
            a2 = fmaf(xv[q].z, sEncW0T[(q * 4 + 2) * 64 + lane], a2);
            a3 = fmaf(xv[q].w, sEncW0T[(q * 4 + 3) * 64 + lane], a3);
        }
        const float hj = fmaxf((a0 + a1) + (a2 + a3), 0.f);
        __builtin_amdgcn_wave_barrier();
        hb[lane] = hj;
        __builtin_amdgcn_wave_barrier();
        float4 hv[8];
        #pragma unroll
        for (int q = 0; q < 8; ++q) hv[q] = *(const float4*)&hb[H + q * 4];
        float c0 = 0.f, c1 = 0.f, c2 = 0.f, c3 = 0.f;
        #pragma unroll
        for (int q = 0; q < 8; ++q) {
            c0 = fmaf(hv[q].x, sEncW1T[(H + q * 4 + 0) * 32 + m], c0);
            c1 = fmaf(hv[q].y, sEncW1T[(H + q * 4 + 1) * 32 + m], c1);
            c2 = fmaf(hv[q].z, sEncW1T[(H + q * 4 + 2) * 32 + m], c2);
            c3 = fmaf(hv[q].w, sEncW1T[(H + q * 4 + 3) * 32 + m], c3);
        }
        float part = (c0 + c1) + (c2 + c3);
        part += __shfl_xor(part, 32, 64);
        return part + sEncB1[m];
    };

    // ---- ystar init (one-time, per element): ystar = W0y[lane,:].y
    auto ystar_init = [&](float yv, float* xb) -> float {
        __builtin_amdgcn_wave_barrier();
        xb[m] = yv;                       // both pair-lanes: same addr, same data
        __builtin_amdgcn_wave_barrier();
        float ys = 0.f;
        #pragma unroll
        for (int q = 0; q < 8; ++q) {
            const float4 wv = *(const float4*)&dynW0[lane * 48 + q * 4];
            const float4 xv = *(const float4*)&xb[q * 4];
            ys = fmaf(wv.x, xv.x, ys); ys = fmaf(wv.y, xv.y, ys);
            ys = fmaf(wv.z, xv.z, ys); ys = fmaf(wv.w, xv.w, ys);
        }
        return ys;
    };

    float yA = encode(bu0, xbA, hbA);
    float yB = encode(bu1, xbB, hbB);
    float ystarA = ystar_init(yA, xbA);
    float ystarB = ystar_init(yB, xbB);

    // per-lane acl partial: aclPart = sum_k w0[lane][32+k] * acl[k]
    auto acl_part = [&](const float* __restrict__ ap) -> float {
        float ar[16];
        #pragma unroll
        for (int q = 0; q < 4; ++q) *(float4*)&ar[q * 4] = *(const float4*)&ap[q * 4];
        const v2f* a2 = (const v2f*)ar;
        const v2f* wq = (const v2f*)wa;
        v2f s0 = mkv2(0.f, 0.f), s1 = mkv2(0.f, 0.f);
        #pragma unroll
        for (int q = 0; q < 8; q += 2) {
            s0 = pkfma(a2[q],     wq[q],     s0);
            s1 = pkfma(a2[q + 1], wq[q + 1], s1);
        }
        const v2f s = s0 + s1;
        return s.x + s.y;
    };

    auto store_y = [&](float yv, int bu, int t) {
        if (lane < 32) yio[(size_t)(bu * NT + t) * 64 + lane] = yv;
    };

    float aclCA = acl_part(aclws + (size_t)(bu0 * NT) * 16);
    float aclCB = acl_part(aclws + (size_t)(bu1 * NT) * 16);
    store_y(yA, bu0, 0);
    store_y(yB, bu1, 0);

    const int tb0 = e0 * NT;
    const int tb1 = (e0 + 1) * NT;

    for (int i = 0; i < NT - 1; ++i) {
        const float t0A = tbuf[tb0 + i], t1A = tbuf[tb0 + i + 1];
        const float t0B = tbuf[tb1 + i], t1B = tbuf[tb1 + i + 1];
        const float hhA = (t1A - t0A) * 0.5f;                       // /K, K=2
        const float hhB = (t1B - t0B) * 0.5f;
        const float aclNA = acl_part(aclws + (size_t)(bu0 * NT + i + 1) * 16);
        const float aclNB = acl_part(aclws + (size_t)(bu1 * NT + i + 1) * 16);
        float haccSA = 0.f, haccSB = 0.f;

        #pragma unroll 1
        for (int sub = 0; sub < 2; ++sub) {
            const float tsubA = t0A + (float)sub * hhA;
            const float tsubB = t0B + (float)sub * hhB;
            // stage-6 time fl(tsub+hh): matches reference searchsorted('right')
            const bool swap6A = (tsubA + hhA >= t1A);
            const bool swap6B = (tsubB + hhB >= t1B);

            const float a1A = ystarA + b0r + aclCA;
            const float a1B = ystarB + b0r + aclCB;

            float g1A, g1B, g2A, g2B, g3A, g3B, g4A, g4B, g5A, g5B;

            const float h1A = fmaxf(a1A, 0.f);
            const float h1B = fmaxf(a1B, 0.f);
            gproj2(h1A, h1B, g1A, g1B); g1A *= hhA; g1B *= hhB;

            const float h2A = fmaxf(fmaf(0.2f, g1A, a1A), 0.f);
            const float h2B = fmaxf(fmaf(0.2f, g1B, a1B), 0.f);
            gproj2(h2A, h2B, g2A, g2B); g2A *= hhA; g2B *= hhB;

            const float h3A = fmaxf(fmaf(0.075f, g1A, fmaf(0.225f, g2A, a1A)), 0.f);
            const float h3B = fmaxf(fmaf(0.075f, g1B, fmaf(0.225f, g2B, a1B)), 0.f);
            gproj2(h3A, h3B, g3A, g3B); g3A *= hhA; g3B *= hhB;

            const float h4A = fmaxf(
                fmaf((float)(44.0/45.0), g1A,
                fmaf((float)(-56.0/15.0), g2A,
                fmaf((float)(32.0/9.0), g3A, a1A))), 0.f);
            const float h4B = fmaxf(
                fmaf((float)(44.0/45.0), g1B,
                fmaf((float)(-56.0/15.0), g2B,
                fmaf((float)(32.0/9.0), g3B, a1B))), 0.f);
            gproj2(h4A, h4B, g4A, g4B); g4A *= hhA; g4B *= hhB;

            const float h5A = fmaxf(
                fmaf((float)(19372.0/6561.0), g1A,
                fmaf((float)(-25360.0/2187.0), g2A,
                fmaf((float)(64448.0/6561.0), g3A,
                fmaf((float)(-212.0/729.0), g4A, a1A)))), 0.f);
            const float h5B = fmaxf(
                fmaf((float)(19372.0/6561.0), g1B,
                fmaf((float)(-25360.0/2187.0), g2B,
                fmaf((float)(64448.0/6561.0), g3B,
                fmaf((float)(-212.0/729.0), g4B, a1B)))), 0.f);
            gproj2(h5A, h5B, g5A, g5B); g5A *= hhA; g5B *= hhB;

            float a6A =
                fmaf((float)(9017.0/3168.0), g1A,
                fmaf((float)(-355.0/33.0), g2A,
                fmaf((float)(46732.0/5247.0), g3A,
                fmaf((float)(49.0/176.0), g4A,
                fmaf((float)(-5103.0/18656.0), g5A, a1A)))));
            float a6B =
                fmaf((float)(9017.0/3168.0), g1B,
                fmaf((float)(-355.0/33.0), g2B,
                fmaf((float)(46732.0/5247.0), g3B,
                fmaf((float)(49.0/176.0), g4B,
                fmaf((float)(-5103.0/18656.0), g5B, a1B)))));
            a6A += swap6A ? (aclNA - aclCA) : 0.f;
            a6B += swap6B ? (aclNB - aclCB) : 0.f;
            const float h6A = fmaxf(a6A, 0.f);
            const float h6B = fmaxf(a6B, 0.f);

            // hacc = sum_s B_s h_s  (B2 = 0)
            float haA = (float)(35.0/384.0) * h1A;
            haA = fmaf((float)(500.0/1113.0),   h3A, haA);
            haA = fmaf((float)(125.0/192.0),    h4A, haA);
            haA = fmaf((float)(-2187.0/6784.0), h5A, haA);
            haA = fmaf((float)(11.0/84.0),      h6A, haA);
            float haB = (float)(35.0/384.0) * h1B;
            haB = fmaf((float)(500.0/1113.0),   h3B, haB);
            haB = fmaf((float)(125.0/192.0),    h4B, haB);
            haB = fmaf((float)(-2187.0/6784.0), h5B, haB);
            haB = fmaf((float)(11.0/84.0),      h6B, haB);

            // ystar advance: W0y.y_next = W0y.y + hh*(M.hacc + v)
            float gaA, gaB;
            gproj2(haA, haB, gaA, gaB);
            ystarA = fmaf(hhA, gaA, ystarA);
            ystarB = fmaf(hhB, gaB, ystarB);
            haccSA += haA;
            haccSB += haB;
        }

        // y materialization, once per interval: y += hh*(W1.haccS + 2*b1)
        {
            __builtin_amdgcn_wave_barrier();
            hbA[lane] = haccSA;
            hbB[lane] = haccSB;
            __builtin_amdgcn_wave_barrier();
            float hrA[32], hrB[32];
            #pragma unroll
            for (int q = 0; q < 8; ++q) *(float4*)&hrA[q * 4] = *(const float4*)&hbA[H + q * 4];
            #pragma unroll
            for (int q = 0; q < 8; ++q) *(float4*)&hrB[q * 4] = *(const float4*)&hbB[H + q * 4];
            const v2f* hpA = (const v2f*)hrA;
            const v2f* hpB = (const v2f*)hrB;
            v2f cA0 = mkv2(0.f, 0.f), cA1 = mkv2(0.f, 0.f);
            v2f cB0 = mkv2(0.f, 0.f), cB1 = mkv2(0.f, 0.f);
            #pragma unroll
            for (int q = 0; q < 16; q += 2) {
                cA0 = pkfma(hpA[q],     w1r[q],     cA0);
                cA1 = pkfma(hpA[q + 1], w1r[q + 1], cA1);
                cB0 = pkfma(hpB[q],     w1r[q],     cB0);
                cB1 = pkfma(hpB[q + 1], w1r[q + 1], cB1);
            }
            float partA = (cA0.x + cA1.x) + (cA0.y + cA1.y);
            float partB = (cB0.x + cB1.x) + (cB0.y + cB1.y);
            partA += __shfl_xor(partA, 32, 64);
            partB += __shfl_xor(partB, 32, 64);
            yA = fmaf(hhA, partA + 2.f * b1r, yA);
            yB = fmaf(hhB, partB + 2.f * b1r, yB);
        }
        aclCA = aclNA;
        aclCB = aclNB;
        store_y(yA, bu0, i + 1);
        store_y(yB, bu1, i + 1);
    }
}

// ---------------------------------------------------------------------------
// Kernel 3: decoder, one thread per (b,t) row, IN PLACE on out. Packed fp32.
// ---------------------------------------------------------------------------
__global__ __launch_bounds__(256, 2) void dec_kernel(
    const float* __restrict__ decW0, const float* __restrict__ decb0,
    const float* __restrict__ decW1, const float* __restrict__ decb1,
    float* __restrict__ yio)
{
    __shared__ float sW0[64 * 32];   // [j][k] as stored
    __shared__ float sW1T[64 * 64];  // [j][n]
    __shared__ float sB0[64];
    __shared__ float sB1[64];
    const int tid = threadIdx.x;
    for (int i = tid; i < 64 * 32; i += 256) sW0[i] = decW0[i];
    for (int i = tid; i < 64 * 64; i += 256) { int n = i >> 6, j = i & 63; sW1T[j * 64 + n] = decW1[i]; }
    if (tid < 64) { sB0[tid] = decb0[tid]; sB1[tid] = decb1[tid]; }
    __syncthreads();

    const size_t row = (size_t)blockIdx.x * 256 + tid;
    float* rp = &yio[row * 64];

    float xr[32];
    #pragma unroll
    for (int q = 0; q < 8; ++q) *(float4*)&xr[q * 4] = *(const float4*)&rp[q * 4];

    v2f o2[32];
    #pragma unroll
    for (int n = 0; n < 32; ++n) o2[n] = mkv2(sB1[2 * n], sB1[2 * n + 1]);

    #pragma unroll 4
    for (int j = 0; j < 64; ++j) {
        v2f a0 = mkv2(sB0[j], 0.f), a1 = mkv2(0.f, 0.f);
        #pragma unroll
        for (int q = 0; q < 8; ++q) {
            const float4 wv = *(const float4*)&sW0[j * 32 + q * 4];
            a0 = pkfma(*(const v2f*)&xr[q * 4],     mkv2(wv.x, wv.y), a0);
            a1 = pkfma(*(const v2f*)&xr[q * 4 + 2], mkv2(wv.z, wv.w), a1);
        }
        const float hj = fmaxf((a0.x + a1.x) + (a0.y + a1.y), 0.f);
        const v2f h2 = mkv2(hj, hj);
        #pragma unroll
        for (int q = 0; q < 16; ++q) {
            const float4 wv = *(const float4*)&sW1T[j * 64 + q * 4];
            o2[2 * q]     = pkfma(h2, mkv2(wv.x, wv.y), o2[2 * q]);
            o2[2 * q + 1] = pkfma(h2, mkv2(wv.z, wv.w), o2[2 * q + 1]);
        }
    }

    #pragma unroll
    for (int q = 0; q < 16; ++q)
        *(float4*)&rp[q * 4] = make_float4(o2[2 * q].x, o2[2 * q].y,
                                           o2[2 * q + 1].x, o2[2 * q + 1].y);
}

extern "C" void kernel_launch(void* const* d_in, const int* in_sizes, int n_in,
                              void* d_out, int out_size, void* d_ws, size_t ws_size,
                              hipStream_t stream)
{
    const float* encW0 = (const float*)d_in[0];
    const float* encb0 = (const float*)d_in[1];
    const float* encW1 = (const float*)d_in[2];
    const float* encb1 = (const float*)d_in[3];
    const float* acW0  = (const float*)d_in[4];
    const float* acb0  = (const float*)d_in[5];
    const float* acW1  = (const float*)d_in[6];
    const float* acb1  = (const float*)d_in[7];
    const float* dynW0 = (const float*)d_in[8];
    const float* dynb0 = (const float*)d_in[9];
    const float* dynW1 = (const float*)d_in[10];
    const float* dynb1 = (const float*)d_in[11];
    const float* decW0 = (const float*)d_in[12];
    const float* decb0 = (const float*)d_in[13];
    const float* decW1 = (const float*)d_in[14];
    const float* decb1 = (const float*)d_in[15];
    const float* ob    = (const float*)d_in[16];
    const float* acs   = (const float*)d_in[17];
    const float* times = (const float*)d_in[18];
    float* out = (float*)d_out;
    float* acl = (float*)d_ws;   // NB*NT*16 floats = 16.8 MB scratch

    acl_kernel<<<(NB * NT) / 256, 256, 0, stream>>>(acs, acW0, acb0, acW1, acb1, acl);
    ode_kernel<<<NB / 8, 256, 0, stream>>>(encW0, encb0, encW1, encb1,
                                           dynW0, dynb0, dynW1, dynb1,
                                           ob, times, acl, out);
    dec_kernel<<<(NB * NT) / 256, 256, 0, stream>>>(decW0, decb0, decW1, decb1, out);
}